// Round 2
// baseline (152.482 us; speedup 1.0000x reference)
//
#include <hip/hip_runtime.h>

#define PI_D 3.14159265358979323846

typedef __attribute__((ext_vector_type(8))) short bf16x8;
typedef __attribute__((ext_vector_type(4))) float f32x4;

static __device__ inline f32x4 mfma16(bf16x8 a, bf16x8 b, f32x4 c) {
    return __builtin_amdgcn_mfma_f32_16x16x32_bf16(a, b, c, 0, 0, 0);
}

static __device__ inline unsigned short f2bf(float f) {
    union { float f; unsigned u; } v; v.f = f;
    unsigned u = v.u;
    u += 0x7fffu + ((u >> 16) & 1u);   // RNE
    return (unsigned short)(u >> 16);
}
static __device__ inline float bf2f(unsigned short h) {
    union { unsigned u; float f; } v; v.u = ((unsigned)h) << 16;
    return v.f;
}

// load 8 consecutive f32 from global, convert to bf16x8 (RNE)
static __device__ inline bf16x8 ld_cvt8(const float* __restrict__ p) {
    float4 v0 = *(const float4*)p;
    float4 v1 = *(const float4*)(p + 4);
    bf16x8 r;
    r[0] = (short)f2bf(v0.x); r[1] = (short)f2bf(v0.y);
    r[2] = (short)f2bf(v0.z); r[3] = (short)f2bf(v0.w);
    r[4] = (short)f2bf(v1.x); r[5] = (short)f2bf(v1.y);
    r[6] = (short)f2bf(v1.z); r[7] = (short)f2bf(v1.w);
    return r;
}

// ---- ws float layout (mode-major intermediates) -------------------------------------
#define OFF_TAB 0                          // 32768 bf16 = 16384 floats
#define OFF_W3T 16384                      // w3T[mode][o*32+i] float2 : 1,048,576 floats
#define OFF_XFT (16384 + 1048576)          // xfT[mode][b*32+i] float2 : 1,048,576 floats
#define OFF_ZMT (16384 + 2 * 1048576)      // zmT[mode][b*32+o] float2 : 1,048,576 floats
// total ~ 12.6 MB

// table offsets in u16 units within OFF_TAB
#define TAB_E1 0        // [32 n=c*16+ky][128 w]
#define TAB_A2 4096     // [64 row=p*32+m][256 k=c*128+x]
#define TAB_A3 20480    // [128 x][64 k=c*32+m]
#define TAB_E4 28672    // [128 y][32 k=p*16+ky]

// ---------------- fused prep: tables (blocks 0..127) + weight relayout (128..1151) ----
__global__ __launch_bounds__(256) void k_prep(const float* __restrict__ wr,
                                              const float* __restrict__ wi,
                                              float* ws) {
    int blk = blockIdx.x, t = threadIdx.x;
    if (blk < 128) {
        int gid = blk * 256 + t;            // 0..32767
        unsigned short* tab = (unsigned short*)(ws + OFF_TAB);
        const float W128 = (float)(2.0 * PI_D / 128.0);
        if (gid < 4096) {                       // E1t: forward y-DFT, x(1/128) scale
            int n = gid >> 7, w = gid & 127;
            int ky = n & 15, c = n >> 4;
            float th = ((w * ky) & 127) * W128;
            float val = (c ? -sinf(th) : cosf(th)) * (1.f / 128.f);
            tab[TAB_E1 + gid] = f2bf(val);
        } else if (gid < 20480) {               // A2: forward x-DFT (complex-as-real)
            int idx = gid - 4096;
            int row = idx >> 8, k = idx & 255;
            int p = row >> 5, m = row & 31;
            int c = k >> 7, xx = k & 127;
            int kx = (m < 16) ? m : 96 + m;
            float th = ((xx * kx) & 127) * W128;
            float er = cosf(th), ei = -sinf(th);
            float val = (p == 0) ? (c == 0 ? er : -ei) : (c == 0 ? ei : er);
            tab[TAB_A2 + idx] = f2bf(val);
        } else if (gid < 28672) {               // A3: inverse x-DFT
            int idx = gid - 20480;
            int xx = idx >> 6, k = idx & 63;
            int c = k >> 5, m = k & 31;
            int kx = (m < 16) ? m : 96 + m;
            float th = ((xx * kx) & 127) * W128;
            float er = cosf(th), ei = sinf(th);
            float val = (c == 0) ? er : -ei;
            tab[TAB_A3 + idx] = f2bf(val);
        } else {                                // E4t: inverse y-DFT w/ hermitian weights
            int idx = gid - 28672;
            int y = idx >> 5, k = idx & 31;
            int p = k >> 4, ky = k & 15;
            float th = ((y * ky) & 127) * W128;
            float sc = (ky == 0 ? 1.f : 2.f) / 128.f;
            float val = (p == 0) ? sc * cosf(th) : -sc * sinf(th);
            tab[TAB_E4 + idx] = f2bf(val);
        }
    } else {
        int bid = blk - 128;             // o*32 + i
        int o = bid >> 5, i = bid & 31;
        const float* r  = wr + (size_t)(i * 32 + o) * 512;
        const float* im = wi + (size_t)(i * 32 + o) * 512;
        float2* dst = (float2*)(ws + OFF_W3T);   // mode-major
        dst[(size_t)t * 1024 + bid]         = make_float2(r[t],       im[t]);
        dst[(size_t)(t + 256) * 1024 + bid] = make_float2(r[t + 256], im[t + 256]);
    }
}

// ---------------- forward: x[bid,:,:] --MFMA--> xfT[mode][bid] ------------------------
__global__ __launch_bounds__(256) void k_f(const float* __restrict__ x, float* ws) {
    __shared__ __align__(16) unsigned short Yl[16 * 264];    // Y: [ky][k=c*128+x]
    int t = threadIdx.x, bid = blockIdx.x;
    const unsigned short* tab = (const unsigned short*)(ws + OFF_TAB);
    int lid = t & 15, q = (t >> 4) & 3, w = t >> 6;
    const float* xim = x + (size_t)bid * 16384;

    // F1: C[x][(c,ky)] = sum_w X[x][w] E1t[(c,ky)][w];  M=128 N=32 K=128
    f32x4 acc[2][2] = {};
#pragma unroll
    for (int ks = 0; ks < 4; ++ks) {
        bf16x8 a0 = ld_cvt8(xim + (32 * w + lid) * 128 + ks * 32 + q * 8);
        bf16x8 a1 = ld_cvt8(xim + (32 * w + 16 + lid) * 128 + ks * 32 + q * 8);
        bf16x8 b0 = *(const bf16x8*)&tab[TAB_E1 + lid * 128 + ks * 32 + q * 8];
        bf16x8 b1 = *(const bf16x8*)&tab[TAB_E1 + (16 + lid) * 128 + ks * 32 + q * 8];
        acc[0][0] = mfma16(a0, b0, acc[0][0]);
        acc[0][1] = mfma16(a0, b1, acc[0][1]);
        acc[1][0] = mfma16(a1, b0, acc[1][0]);
        acc[1][1] = mfma16(a1, b1, acc[1][1]);
    }
    // epilogue: Y -> Yl[ky][c*128+x] bf16
#pragma unroll
    for (int mt = 0; mt < 2; ++mt)
#pragma unroll
        for (int nt = 0; nt < 2; ++nt) {
            ushort4 h;
            h.x = f2bf(acc[mt][nt][0]); h.y = f2bf(acc[mt][nt][1]);
            h.z = f2bf(acc[mt][nt][2]); h.w = f2bf(acc[mt][nt][3]);
            *(ushort4*)&Yl[lid * 264 + nt * 128 + 32 * w + mt * 16 + q * 4] = h;
        }
    __syncthreads();

    // F2: C[(p,m)][ky] = sum_k A2[(p,m)][k] Yl[ky][k];  M=64 N=16 K=256
    f32x4 acc2 = {};
    const unsigned short* A2g = tab + TAB_A2;
#pragma unroll
    for (int ks = 0; ks < 8; ++ks) {
        bf16x8 a = *(const bf16x8*)&A2g[(16 * w + lid) * 256 + ks * 32 + q * 8];
        bf16x8 b = *(const bf16x8*)&Yl[lid * 264 + ks * 32 + q * 8];
        acc2 = mfma16(a, b, acc2);
    }
    int p = w >> 1, mb = (w & 1) * 16;
    float* xft = ws + OFF_XFT;
#pragma unroll
    for (int r = 0; r < 4; ++r) {
        int mode = (mb + q * 4 + r) * 16 + lid;
        xft[((size_t)mode * 1024 + bid) * 2 + p] = acc2[r];   // scattered 4B, fire-and-forget
    }
}

// ---------------- channel mix per mode: zmT[mode][b*32+o] = sum_i xfT*w3T -------------
// One block per mode: operands are 8KB each -> LDS, full reuse.
// Total traffic 8MB read + 4MB write (was 268MB inside k_im).
__global__ __launch_bounds__(256) void k_mix(float* ws) {
    __shared__ float2 xl[1024];          // [b*32+i]
    __shared__ float2 wl[32 * 33];       // [i][o], pad 33 to kill bank conflicts
    int t = threadIdx.x, mode = blockIdx.x;
    const float2* xg = (const float2*)(ws + OFF_XFT) + (size_t)mode * 1024;
    const float2* wg = (const float2*)(ws + OFF_W3T) + (size_t)mode * 1024;
#pragma unroll
    for (int c = 0; c < 4; ++c) {
        int row = t + 256 * c;           // row = o*32+i
        xl[row] = xg[row];
        float2 wv = wg[row];
        wl[(row & 31) * 33 + (row >> 5)] = wv;
    }
    __syncthreads();
    int o = t & 31, b0 = t >> 5;
    float zr[4] = {0.f, 0.f, 0.f, 0.f}, zi[4] = {0.f, 0.f, 0.f, 0.f};
#pragma unroll 4
    for (int i = 0; i < 32; ++i) {
        float2 w2 = wl[i * 33 + o];
#pragma unroll
        for (int c = 0; c < 4; ++c) {
            float2 x2 = xl[(b0 + 8 * c) * 32 + i];
            // identical op order to the original f32 mix (bit-exact)
            zr[c] = fmaf(x2.x, w2.x, fmaf(-x2.y, w2.y, zr[c]));
            zi[c] = fmaf(x2.x, w2.y, fmaf( x2.y, w2.x, zi[c]));
        }
    }
    float2* zg = (float2*)(ws + OFF_ZMT) + (size_t)mode * 1024;
#pragma unroll
    for (int c = 0; c < 4; ++c)
        zg[t + 256 * c] = make_float2(zr[c], zi[c]);
}

// ---------------- inverse: block (b,o) -> out[b,o,:,:] --------------------------------
// Mix already done: just gather zm[512] (4KB) and run I1/I2 with split-bf16.
__global__ __launch_bounds__(256) void k_im(const float* __restrict__ ws, float* __restrict__ out) {
    __shared__ __align__(16) unsigned short Zlh[128 * 40];   // [x][k=p*16+ky] hi
    __shared__ __align__(16) unsigned short Zll[128 * 40];   // lo residual
    __shared__ __align__(16) unsigned short Blh[32 * 72];    // [(p,ky)][k=c*32+m] hi
    __shared__ __align__(16) unsigned short Bll[32 * 72];    // lo residual
    __shared__ float2 zm[512];
    int t = threadIdx.x, bid = blockIdx.x;                   // b*32 + o
    const unsigned short* tab = (const unsigned short*)(ws + OFF_TAB);

    // gather this (b,o)'s 512 mixed modes (8B strided reads, L2-resident)
    {
        const float2* zg = (const float2*)(ws + OFF_ZMT);
        zm[t]       = zg[(size_t)t * 1024 + bid];
        zm[t + 256] = zg[(size_t)(t + 256) * 1024 + bid];
    }
    __syncthreads();

    // build Blh/Bll from zm (complex-as-real with sign trick; hi + residual-lo)
    {
        int n = t >> 3, k0 = (t & 7) * 8;
        int p = n >> 4, ky = n & 15;
        unsigned short hh[8], hl[8];
#pragma unroll
        for (int j = 0; j < 8; ++j) {
            int k = k0 + j, c = k >> 5, m = k & 31;
            float2 v = zm[m * 16 + ky];
            float val = (p == 0) ? (c == 0 ? v.x : v.y) : (c == 0 ? v.y : -v.x);
            unsigned short vh = f2bf(val);
            hh[j] = vh;
            hl[j] = f2bf(val - bf2f(vh));
        }
        ushort4 a, bb;
        a.x = hh[0]; a.y = hh[1]; a.z = hh[2]; a.w = hh[3];
        bb.x = hh[4]; bb.y = hh[5]; bb.z = hh[6]; bb.w = hh[7];
        *(ushort4*)&Blh[n * 72 + k0]     = a;
        *(ushort4*)&Blh[n * 72 + k0 + 4] = bb;
        a.x = hl[0]; a.y = hl[1]; a.z = hl[2]; a.w = hl[3];
        bb.x = hl[4]; bb.y = hl[5]; bb.z = hl[6]; bb.w = hl[7];
        *(ushort4*)&Bll[n * 72 + k0]     = a;
        *(ushort4*)&Bll[n * 72 + k0 + 4] = bb;
    }
    __syncthreads();

    int lid = t & 15, q = (t >> 4) & 3, w = t >> 6;

    // I1: Z[x][(p,ky)] = sum_k A3[x][k] (Bh+Bl)[(p,ky)][k];  M=128 N=32 K=64, double-pumped
    f32x4 acc[2][2] = {};
#pragma unroll
    for (int ks = 0; ks < 2; ++ks) {
        bf16x8 a0  = *(const bf16x8*)&tab[TAB_A3 + (32 * w + lid) * 64 + ks * 32 + q * 8];
        bf16x8 a1  = *(const bf16x8*)&tab[TAB_A3 + (32 * w + 16 + lid) * 64 + ks * 32 + q * 8];
        bf16x8 bh0 = *(const bf16x8*)&Blh[lid * 72 + ks * 32 + q * 8];
        bf16x8 bh1 = *(const bf16x8*)&Blh[(16 + lid) * 72 + ks * 32 + q * 8];
        bf16x8 bl0 = *(const bf16x8*)&Bll[lid * 72 + ks * 32 + q * 8];
        bf16x8 bl1 = *(const bf16x8*)&Bll[(16 + lid) * 72 + ks * 32 + q * 8];
        acc[0][0] = mfma16(a0, bl0, acc[0][0]);
        acc[0][0] = mfma16(a0, bh0, acc[0][0]);
        acc[0][1] = mfma16(a0, bl1, acc[0][1]);
        acc[0][1] = mfma16(a0, bh1, acc[0][1]);
        acc[1][0] = mfma16(a1, bl0, acc[1][0]);
        acc[1][0] = mfma16(a1, bh0, acc[1][0]);
        acc[1][1] = mfma16(a1, bl1, acc[1][1]);
        acc[1][1] = mfma16(a1, bh1, acc[1][1]);
    }
    // epilogue: Z -> Zlh/Zll[x][p*16+ky] (hi + residual-lo)
#pragma unroll
    for (int mt = 0; mt < 2; ++mt)
#pragma unroll
        for (int nt = 0; nt < 2; ++nt)
#pragma unroll
            for (int r = 0; r < 4; ++r) {
                float z = acc[mt][nt][r];
                unsigned short zh = f2bf(z);
                int idx = (32 * w + mt * 16 + q * 4 + r) * 40 + nt * 16 + lid;
                Zlh[idx] = zh;
                Zll[idx] = f2bf(z - bf2f(zh));
            }
    __syncthreads();

    // I2: out[x][y] = sum_k (Zh+Zl)[x][k] E4t[y][k];  M=128 N=128 K=32, double-pumped
    f32x4 acc2[2][8];
#pragma unroll
    for (int mt = 0; mt < 2; ++mt) {
        bf16x8 ah = *(const bf16x8*)&Zlh[(32 * w + mt * 16 + lid) * 40 + q * 8];
        bf16x8 al = *(const bf16x8*)&Zll[(32 * w + mt * 16 + lid) * 40 + q * 8];
#pragma unroll
        for (int nt = 0; nt < 8; ++nt) {
            bf16x8 bb = *(const bf16x8*)&tab[TAB_E4 + (nt * 16 + lid) * 32 + q * 8];
            f32x4 z = {};
            z = mfma16(al, bb, z);
            acc2[mt][nt] = mfma16(ah, bb, z);
        }
    }
    float* og = out + (size_t)bid * 16384;
#pragma unroll
    for (int mt = 0; mt < 2; ++mt)
#pragma unroll
        for (int r = 0; r < 4; ++r)
#pragma unroll
            for (int nt = 0; nt < 8; ++nt)
                og[(32 * w + mt * 16 + q * 4 + r) * 128 + nt * 16 + lid] = acc2[mt][nt][r];
}

extern "C" void kernel_launch(void* const* d_in, const int* in_sizes, int n_in,
                              void* d_out, int out_size, void* d_ws, size_t ws_size,
                              hipStream_t stream) {
    const float* x  = (const float*)d_in[0];
    const float* wr = (const float*)d_in[1];
    const float* wi = (const float*)d_in[2];
    float* out = (float*)d_out;
    float* ws  = (float*)d_ws;
    k_prep<<<dim3(1152), dim3(256), 0, stream>>>(wr, wi, ws);
    k_f   <<<dim3(1024), dim3(256), 0, stream>>>(x, ws);
    k_mix <<<dim3(512),  dim3(256), 0, stream>>>(ws);
    k_im  <<<dim3(1024), dim3(256), 0, stream>>>(ws, out);
}

// Round 3
// 134.920 us; speedup vs baseline: 1.1302x; 1.1302x over previous
//
#include <hip/hip_runtime.h>

#define PI_D 3.14159265358979323846

typedef __attribute__((ext_vector_type(8))) short bf16x8;
typedef __attribute__((ext_vector_type(4))) float f32x4;

static __device__ inline f32x4 mfma16(bf16x8 a, bf16x8 b, f32x4 c) {
    return __builtin_amdgcn_mfma_f32_16x16x32_bf16(a, b, c, 0, 0, 0);
}

static __device__ inline unsigned short f2bf(float f) {
    union { float f; unsigned u; } v; v.f = f;
    unsigned u = v.u;
    u += 0x7fffu + ((u >> 16) & 1u);   // RNE
    return (unsigned short)(u >> 16);
}
static __device__ inline float bf2f(unsigned short h) {
    union { unsigned u; float f; } v; v.u = ((unsigned)h) << 16;
    return v.f;
}

// load 8 consecutive f32 from global, convert to bf16x8 (RNE)
static __device__ inline bf16x8 ld_cvt8(const float* __restrict__ p) {
    float4 v0 = *(const float4*)p;
    float4 v1 = *(const float4*)(p + 4);
    bf16x8 r;
    r[0] = (short)f2bf(v0.x); r[1] = (short)f2bf(v0.y);
    r[2] = (short)f2bf(v0.z); r[3] = (short)f2bf(v0.w);
    r[4] = (short)f2bf(v1.x); r[5] = (short)f2bf(v1.y);
    r[6] = (short)f2bf(v1.z); r[7] = (short)f2bf(v1.w);
    return r;
}

// ---- ws float layout ----------------------------------------------------------------
#define OFF_TAB 0                         // 32768 bf16 = 16384 floats (only A3/E4 used)
#define OFF_WT3  16384                    // wt3[o*32+i][mode] cplx: 1024*512 float2
#define OFF_XFR  (16384 + 1048576)        // 1024 bids x 512 modes f32 (re)
#define OFF_XFI  (OFF_XFR + 524288)       // (im)

// table offsets in u16 units within OFF_TAB
#define TAB_A3 20480    // [128 x][64 k=c*32+m]
#define TAB_E4 28672    // [128 y][32 k=p*16+ky]

// ---------------- forward + all prep: 2-kernel pipeline, kernel 1 ---------------------
// Per block (b,i): forward transform of one image. Twiddles have only 128 distinct
// angles -> 1 KB LDS cos/sin table (1 sincos/thread), E1/A2 MFMA fragments generated
// in registers from it (bit-identical values to the old precomputed tables).
// Side duties: w3 relayout slice (all blocks), A3/E4 global tables (blocks 0/1).
__global__ __launch_bounds__(256) void k_f(const float* __restrict__ x,
                                           const float* __restrict__ wr,
                                           const float* __restrict__ wi,
                                           float* ws) {
    __shared__ float c128[128], s128[128];
    __shared__ __align__(16) unsigned short Yl[16 * 264];    // Y: [ky][k=c*128+x]
    int t = threadIdx.x, bid = blockIdx.x;
    const float W128 = (float)(2.0 * PI_D / 128.0);
    if (t < 128) { float th = t * W128; c128[t] = cosf(th); s128[t] = sinf(th); }

    // side duty (no LDS dep): w3 relayout, chunk bid = o*32+i
    {
        int o = bid >> 5, i = bid & 31;
        const float* r  = wr + (size_t)(i * 32 + o) * 512;
        const float* im = wi + (size_t)(i * 32 + o) * 512;
        float2* dst = (float2*)(ws + OFF_WT3) + (size_t)bid * 512;
        dst[t]       = make_float2(r[t],       im[t]);
        dst[t + 256] = make_float2(r[t + 256], im[t + 256]);
    }
    __syncthreads();

    // side duty: blocks 0/1 emit the inverse-DFT tables for k_im (bit-identical math)
    unsigned short* tabw = (unsigned short*)(ws + OFF_TAB);
    if (bid == 0) {
        for (int idx = t; idx < 8192; idx += 256) {          // A3: inverse x-DFT
            int xx = idx >> 6, k = idx & 63, c = k >> 5, m = k & 31;
            int kx = (m < 16) ? m : 96 + m;
            int a = (xx * kx) & 127;
            float val = (c == 0) ? c128[a] : -s128[a];
            tabw[TAB_A3 + idx] = f2bf(val);
        }
    } else if (bid == 1) {
        for (int idx = t; idx < 4096; idx += 256) {          // E4t: inverse y-DFT
            int y = idx >> 5, k = idx & 31, p = k >> 4, ky = k & 15;
            int a = (y * ky) & 127;
            float sc = (ky == 0 ? 1.f : 2.f) / 128.f;
            float val = (p == 0) ? sc * c128[a] : -sc * s128[a];
            tabw[TAB_E4 + idx] = f2bf(val);
        }
    }

    int lid = t & 15, q = (t >> 4) & 3, w = t >> 6;
    const float* xim = x + (size_t)bid * 16384;
    const float inv128 = 1.f / 128.f;

    // F1: C[x][(c,ky)] = sum_w X[x][w] E1t[(c,ky)][w];  M=128 N=32 K=128
    // E1 fragments from angle table: row lid -> ky=lid,c=0 (cos); row 16+lid -> c=1 (-sin)
    f32x4 acc[2][2] = {};
#pragma unroll
    for (int ks = 0; ks < 4; ++ks) {
        bf16x8 a0 = ld_cvt8(xim + (32 * w + lid) * 128 + ks * 32 + q * 8);
        bf16x8 a1 = ld_cvt8(xim + (32 * w + 16 + lid) * 128 + ks * 32 + q * 8);
        bf16x8 b0, b1;
#pragma unroll
        for (int j = 0; j < 8; ++j) {
            int a = ((ks * 32 + q * 8 + j) * lid) & 127;
            b0[j] = (short)f2bf(c128[a] * inv128);
            b1[j] = (short)f2bf(-s128[a] * inv128);
        }
        acc[0][0] = mfma16(a0, b0, acc[0][0]);
        acc[0][1] = mfma16(a0, b1, acc[0][1]);
        acc[1][0] = mfma16(a1, b0, acc[1][0]);
        acc[1][1] = mfma16(a1, b1, acc[1][1]);
    }
    // epilogue: Y -> Yl[ky][c*128+x] bf16
#pragma unroll
    for (int mt = 0; mt < 2; ++mt)
#pragma unroll
        for (int nt = 0; nt < 2; ++nt) {
            ushort4 h;
            h.x = f2bf(acc[mt][nt][0]); h.y = f2bf(acc[mt][nt][1]);
            h.z = f2bf(acc[mt][nt][2]); h.w = f2bf(acc[mt][nt][3]);
            *(ushort4*)&Yl[lid * 264 + nt * 128 + 32 * w + mt * 16 + q * 4] = h;
        }
    __syncthreads();

    // F2: C[(p,m)][ky] = sum_k A2[(p,m)][k] Yl[ky][k];  M=64 N=16 K=256
    // A2 fragments from angle table (row = 16w+lid)
    f32x4 acc2 = {};
    {
        int row = 16 * w + lid, p = row >> 5, m = row & 31;
        int kx = (m < 16) ? m : 96 + m;
#pragma unroll
        for (int ks = 0; ks < 8; ++ks) {
            bf16x8 a;
#pragma unroll
            for (int j = 0; j < 8; ++j) {
                int k = ks * 32 + q * 8 + j, c = k >> 7, xx = k & 127;
                int ang = (xx * kx) & 127;
                float er = c128[ang], ei = -s128[ang];
                float val = (p == 0) ? (c == 0 ? er : -ei) : (c == 0 ? ei : er);
                a[j] = (short)f2bf(val);
            }
            bf16x8 b = *(const bf16x8*)&Yl[lid * 264 + ks * 32 + q * 8];
            acc2 = mfma16(a, b, acc2);
        }
    }
    int p = w >> 1, mb = (w & 1) * 16;
    float* xfp = ws + (p ? OFF_XFI : OFF_XFR) + (size_t)bid * 512;
#pragma unroll
    for (int r = 0; r < 4; ++r)
        xfp[(mb + q * 4 + r) * 16 + lid] = acc2[r];
}

// ---------------- fused mix + inverse: block (b,o) -> out[b,o,:,:] --------------------
// Verbatim R1 version: f32 mix from global xf/w3, A3/E4 from L1-hot global tab,
// split-bf16 (hi+lo) I1/I2. LDS 33KB -> 4 blocks/CU.
__global__ __launch_bounds__(256) void k_im(const float* __restrict__ ws, float* __restrict__ out) {
    __shared__ __align__(16) unsigned short Zlh[128 * 40];   // [x][k=p*16+ky] hi
    __shared__ __align__(16) unsigned short Zll[128 * 40];   // lo residual
    __shared__ __align__(16) unsigned short Blh[32 * 72];    // [(p,ky)][k=c*32+m] hi
    __shared__ __align__(16) unsigned short Bll[32 * 72];    // lo residual
    __shared__ float2 zm[512];
    int t = threadIdx.x, bid = blockIdx.x;                   // b*32 + o
    int b = bid >> 5, o = bid & 31;
    const unsigned short* tab = (const unsigned short*)(ws + OFF_TAB);

    // ---- channel mix, f32: zm[mode] = sum_i xf[b,i,mode] * w3[o,i,mode]
    {
        const float* xfr = ws + OFF_XFR;
        const float* xfi = ws + OFF_XFI;
        const float* w3  = ws + OFF_WT3;     // float2[(o*32+i)*512 + mode]
        float a0r = 0.f, a0i = 0.f, a1r = 0.f, a1i = 0.f;
#pragma unroll 4
        for (int i = 0; i < 32; ++i) {
            const float2 xr2 = *(const float2*)(xfr + (size_t)(b * 32 + i) * 512 + 2 * t);
            const float2 xi2 = *(const float2*)(xfi + (size_t)(b * 32 + i) * 512 + 2 * t);
            const float4 w4  = *(const float4*)(w3 + ((size_t)(o * 32 + i) * 512 + 2 * t) * 2);
            a0r = fmaf(xr2.x, w4.x, fmaf(-xi2.x, w4.y, a0r));
            a0i = fmaf(xr2.x, w4.y, fmaf( xi2.x, w4.x, a0i));
            a1r = fmaf(xr2.y, w4.z, fmaf(-xi2.y, w4.w, a1r));
            a1i = fmaf(xr2.y, w4.w, fmaf( xi2.y, w4.z, a1i));
        }
        zm[2 * t]     = make_float2(a0r, a0i);
        zm[2 * t + 1] = make_float2(a1r, a1i);
    }
    __syncthreads();

    // build Blh/Bll from zm (complex-as-real with sign trick; hi + residual-lo)
    {
        int n = t >> 3, k0 = (t & 7) * 8;
        int p = n >> 4, ky = n & 15;
        unsigned short hh[8], hl[8];
#pragma unroll
        for (int j = 0; j < 8; ++j) {
            int k = k0 + j, c = k >> 5, m = k & 31;
            float2 v = zm[m * 16 + ky];
            float val = (p == 0) ? (c == 0 ? v.x : v.y) : (c == 0 ? v.y : -v.x);
            unsigned short vh = f2bf(val);
            hh[j] = vh;
            hl[j] = f2bf(val - bf2f(vh));
        }
        ushort4 a, bb;
        a.x = hh[0]; a.y = hh[1]; a.z = hh[2]; a.w = hh[3];
        bb.x = hh[4]; bb.y = hh[5]; bb.z = hh[6]; bb.w = hh[7];
        *(ushort4*)&Blh[n * 72 + k0]     = a;
        *(ushort4*)&Blh[n * 72 + k0 + 4] = bb;
        a.x = hl[0]; a.y = hl[1]; a.z = hl[2]; a.w = hl[3];
        bb.x = hl[4]; bb.y = hl[5]; bb.z = hl[6]; bb.w = hl[7];
        *(ushort4*)&Bll[n * 72 + k0]     = a;
        *(ushort4*)&Bll[n * 72 + k0 + 4] = bb;
    }
    __syncthreads();

    int lid = t & 15, q = (t >> 4) & 3, w = t >> 6;

    // I1: Z[x][(p,ky)] = sum_k A3[x][k] (Bh+Bl)[(p,ky)][k];  M=128 N=32 K=64, double-pumped
    f32x4 acc[2][2] = {};
#pragma unroll
    for (int ks = 0; ks < 2; ++ks) {
        bf16x8 a0  = *(const bf16x8*)&tab[TAB_A3 + (32 * w + lid) * 64 + ks * 32 + q * 8];
        bf16x8 a1  = *(const bf16x8*)&tab[TAB_A3 + (32 * w + 16 + lid) * 64 + ks * 32 + q * 8];
        bf16x8 bh0 = *(const bf16x8*)&Blh[lid * 72 + ks * 32 + q * 8];
        bf16x8 bh1 = *(const bf16x8*)&Blh[(16 + lid) * 72 + ks * 32 + q * 8];
        bf16x8 bl0 = *(const bf16x8*)&Bll[lid * 72 + ks * 32 + q * 8];
        bf16x8 bl1 = *(const bf16x8*)&Bll[(16 + lid) * 72 + ks * 32 + q * 8];
        acc[0][0] = mfma16(a0, bl0, acc[0][0]);
        acc[0][0] = mfma16(a0, bh0, acc[0][0]);
        acc[0][1] = mfma16(a0, bl1, acc[0][1]);
        acc[0][1] = mfma16(a0, bh1, acc[0][1]);
        acc[1][0] = mfma16(a1, bl0, acc[1][0]);
        acc[1][0] = mfma16(a1, bh0, acc[1][0]);
        acc[1][1] = mfma16(a1, bl1, acc[1][1]);
        acc[1][1] = mfma16(a1, bh1, acc[1][1]);
    }
    // epilogue: Z -> Zlh/Zll[x][p*16+ky] (hi + residual-lo)
#pragma unroll
    for (int mt = 0; mt < 2; ++mt)
#pragma unroll
        for (int nt = 0; nt < 2; ++nt)
#pragma unroll
            for (int r = 0; r < 4; ++r) {
                float z = acc[mt][nt][r];
                unsigned short zh = f2bf(z);
                int idx = (32 * w + mt * 16 + q * 4 + r) * 40 + nt * 16 + lid;
                Zlh[idx] = zh;
                Zll[idx] = f2bf(z - bf2f(zh));
            }
    __syncthreads();

    // I2: out[x][y] = sum_k (Zh+Zl)[x][k] E4t[y][k];  M=128 N=128 K=32, double-pumped
    f32x4 acc2[2][8];
#pragma unroll
    for (int mt = 0; mt < 2; ++mt) {
        bf16x8 ah = *(const bf16x8*)&Zlh[(32 * w + mt * 16 + lid) * 40 + q * 8];
        bf16x8 al = *(const bf16x8*)&Zll[(32 * w + mt * 16 + lid) * 40 + q * 8];
#pragma unroll
        for (int nt = 0; nt < 8; ++nt) {
            bf16x8 bb = *(const bf16x8*)&tab[TAB_E4 + (nt * 16 + lid) * 32 + q * 8];
            f32x4 z = {};
            z = mfma16(al, bb, z);
            acc2[mt][nt] = mfma16(ah, bb, z);
        }
    }
    float* og = out + (size_t)bid * 16384;
#pragma unroll
    for (int mt = 0; mt < 2; ++mt)
#pragma unroll
        for (int r = 0; r < 4; ++r)
#pragma unroll
            for (int nt = 0; nt < 8; ++nt)
                og[(32 * w + mt * 16 + q * 4 + r) * 128 + nt * 16 + lid] = acc2[mt][nt][r];
}

extern "C" void kernel_launch(void* const* d_in, const int* in_sizes, int n_in,
                              void* d_out, int out_size, void* d_ws, size_t ws_size,
                              hipStream_t stream) {
    const float* x  = (const float*)d_in[0];
    const float* wr = (const float*)d_in[1];
    const float* wi = (const float*)d_in[2];
    float* out = (float*)d_out;
    float* ws  = (float*)d_ws;
    k_f <<<dim3(1024), dim3(256), 0, stream>>>(x, wr, wi, ws);
    k_im<<<dim3(1024), dim3(256), 0, stream>>>(ws, out);
}

// Round 4
// 132.584 us; speedup vs baseline: 1.1501x; 1.0176x over previous
//
#include <hip/hip_runtime.h>

#define PI_D 3.14159265358979323846

typedef __attribute__((ext_vector_type(8))) short bf16x8;
typedef __attribute__((ext_vector_type(4))) float f32x4;

static __device__ inline f32x4 mfma16(bf16x8 a, bf16x8 b, f32x4 c) {
    return __builtin_amdgcn_mfma_f32_16x16x32_bf16(a, b, c, 0, 0, 0);
}

static __device__ inline unsigned short f2bf(float f) {
    union { float f; unsigned u; } v; v.f = f;
    unsigned u = v.u;
    u += 0x7fffu + ((u >> 16) & 1u);   // RNE
    return (unsigned short)(u >> 16);
}
static __device__ inline float bf2f(unsigned short h) {
    union { unsigned u; float f; } v; v.u = ((unsigned)h) << 16;
    return v.f;
}

// load 8 consecutive f32 from global, convert to bf16x8 (RNE)
static __device__ inline bf16x8 ld_cvt8(const float* __restrict__ p) {
    float4 v0 = *(const float4*)p;
    float4 v1 = *(const float4*)(p + 4);
    bf16x8 r;
    r[0] = (short)f2bf(v0.x); r[1] = (short)f2bf(v0.y);
    r[2] = (short)f2bf(v0.z); r[3] = (short)f2bf(v0.w);
    r[4] = (short)f2bf(v1.x); r[5] = (short)f2bf(v1.y);
    r[6] = (short)f2bf(v1.z); r[7] = (short)f2bf(v1.w);
    return r;
}

// ---- ws float layout ----------------------------------------------------------------
#define OFF_TAB 0                         // 32768 bf16 = 16384 floats (only A3/E4 used)
#define OFF_WT3  16384                    // wt3[o*32+i][mode] cplx: 1024*512 float2
#define OFF_XFR  (16384 + 1048576)        // 1024 bids x 512 modes f32 (re)
#define OFF_XFI  (OFF_XFR + 524288)       // (im)

// table offsets in u16 units within OFF_TAB
#define TAB_A3 20480    // [128 x][64 k=c*32+m]
#define TAB_E4 28672    // [128 y][32 k=p*16+ky]

// ---------------- forward + all prep: kernel 1 ----------------------------------------
// Twiddles: 128 distinct angles -> bf16 lookup tables built once (1 sincos/thread).
//   cb/sb: pre-scaled (1/128) E1 values; bc/bs: unscaled A2 values (negate = sign XOR,
//   bit-identical under RNE). E1 fragments are reused by all 4 waves -> staged in LDS
//   as an 8KB bf16 table (136-stride). A2 elements are thread-unique -> generated
//   in registers at ~4 ops/element.
// Side duties: w3 relayout (all blocks), A3/E4 global tables (blocks 0/1).
__global__ __launch_bounds__(256) void k_f(const float* __restrict__ x,
                                           const float* __restrict__ wr,
                                           const float* __restrict__ wi,
                                           float* ws) {
    __shared__ float c128[128], s128[128];
    __shared__ unsigned short cb[128], sb[128], bc[128], bs[128];
    __shared__ __align__(16) unsigned short E1l[32 * 136];   // [n=c*16+ky][w]
    __shared__ __align__(16) unsigned short Yl[16 * 264];    // Y: [ky][k=c*128+x]
    int t = threadIdx.x, bid = blockIdx.x;
    const float W128 = (float)(2.0 * PI_D / 128.0);
    const float inv128 = 1.f / 128.f;
    if (t < 128) {
        float th = t * W128, c = cosf(th), s = sinf(th);
        c128[t] = c; s128[t] = s;
        cb[t] = f2bf(c * inv128);
        sb[t] = f2bf(-s * inv128);
        bc[t] = f2bf(c);
        bs[t] = f2bf(s);
    }

    // side duty (no LDS dep): w3 relayout, chunk bid = o*32+i
    {
        int o = bid >> 5, i = bid & 31;
        const float* r  = wr + (size_t)(i * 32 + o) * 512;
        const float* im = wi + (size_t)(i * 32 + o) * 512;
        float2* dst = (float2*)(ws + OFF_WT3) + (size_t)bid * 512;
        dst[t]       = make_float2(r[t],       im[t]);
        dst[t + 256] = make_float2(r[t + 256], im[t + 256]);
    }
    __syncthreads();

    // build E1l fragment table from cb/sb (each entry reused by 4 waves)
    for (int e = t; e < 4096; e += 256) {
        int row = e >> 7, col = e & 127;
        int ky = row & 15, c = row >> 4;
        int a = (col * ky) & 127;
        E1l[row * 136 + col] = c ? sb[a] : cb[a];
    }

    // side duty: blocks 0/1 emit the inverse-DFT tables for k_im (bit-identical math)
    unsigned short* tabw = (unsigned short*)(ws + OFF_TAB);
    if (bid == 0) {
        for (int idx = t; idx < 8192; idx += 256) {          // A3: inverse x-DFT
            int xx = idx >> 6, k = idx & 63, c = k >> 5, m = k & 31;
            int kx = (m < 16) ? m : 96 + m;
            int a = (xx * kx) & 127;
            float val = (c == 0) ? c128[a] : -s128[a];
            tabw[TAB_A3 + idx] = f2bf(val);
        }
    } else if (bid == 1) {
        for (int idx = t; idx < 4096; idx += 256) {          // E4t: inverse y-DFT
            int y = idx >> 5, k = idx & 31, p = k >> 4, ky = k & 15;
            int a = (y * ky) & 127;
            float sc = (ky == 0 ? 1.f : 2.f) / 128.f;
            float val = (p == 0) ? sc * c128[a] : -sc * s128[a];
            tabw[TAB_E4 + idx] = f2bf(val);
        }
    }
    __syncthreads();

    int lid = t & 15, q = (t >> 4) & 3, w = t >> 6;
    const float* xim = x + (size_t)bid * 16384;

    // F1: C[x][(c,ky)] = sum_w X[x][w] E1t[(c,ky)][w];  M=128 N=32 K=128
    f32x4 acc[2][2] = {};
#pragma unroll
    for (int ks = 0; ks < 4; ++ks) {
        bf16x8 a0 = ld_cvt8(xim + (32 * w + lid) * 128 + ks * 32 + q * 8);
        bf16x8 a1 = ld_cvt8(xim + (32 * w + 16 + lid) * 128 + ks * 32 + q * 8);
        bf16x8 b0 = *(const bf16x8*)&E1l[lid * 136 + ks * 32 + q * 8];
        bf16x8 b1 = *(const bf16x8*)&E1l[(16 + lid) * 136 + ks * 32 + q * 8];
        acc[0][0] = mfma16(a0, b0, acc[0][0]);
        acc[0][1] = mfma16(a0, b1, acc[0][1]);
        acc[1][0] = mfma16(a1, b0, acc[1][0]);
        acc[1][1] = mfma16(a1, b1, acc[1][1]);
    }
    // epilogue: Y -> Yl[ky][c*128+x] bf16
#pragma unroll
    for (int mt = 0; mt < 2; ++mt)
#pragma unroll
        for (int nt = 0; nt < 2; ++nt) {
            ushort4 h;
            h.x = f2bf(acc[mt][nt][0]); h.y = f2bf(acc[mt][nt][1]);
            h.z = f2bf(acc[mt][nt][2]); h.w = f2bf(acc[mt][nt][3]);
            *(ushort4*)&Yl[lid * 264 + nt * 128 + 32 * w + mt * 16 + q * 4] = h;
        }
    __syncthreads();

    // F2: C[(p,m)][ky] = sum_k A2[(p,m)][k] Yl[ky][k];  M=64 N=16 K=256
    // A2 elements are thread-unique: gen from bc/bs at ~4 ops each.
    f32x4 acc2 = {};
    {
        int row = 16 * w + lid, p = row >> 5, m = row & 31;
        int kx = (m < 16) ? m : 96 + m;
#pragma unroll
        for (int ks = 0; ks < 8; ++ks) {
            const bool cc = (ks >= 4);         // c = k>>7, compile-time per ks
            bf16x8 a;
#pragma unroll
            for (int j = 0; j < 8; ++j) {
                int xx = (ks * 32 + q * 8 + j) & 127;
                int ang = (xx * kx) & 127;
                unsigned short v;
                if (p == 0) v = cc ? bs[ang] : bc[ang];                      // er / -ei
                else        v = cc ? bc[ang] : (unsigned short)(bs[ang] ^ 0x8000u); // er / ei
                a[j] = (short)v;
            }
            bf16x8 b = *(const bf16x8*)&Yl[lid * 264 + ks * 32 + q * 8];
            acc2 = mfma16(a, b, acc2);
        }
    }
    int p = w >> 1, mb = (w & 1) * 16;
    float* xfp = ws + (p ? OFF_XFI : OFF_XFR) + (size_t)bid * 512;
#pragma unroll
    for (int r = 0; r < 4; ++r)
        xfp[(mb + q * 4 + r) * 16 + lid] = acc2[r];
}

// ---------------- fused mix + inverse: block (b, o-quad) -> out[b,4o,:,:] -------------
// o-quad register blocking: each xf read is shared by 4 outputs (mix L2/L3 traffic
// 268MB -> 164MB, 4x FMA ILP). I1/I2 loop over the 4 o's reusing LDS buffers.
// FMA order per output identical to before (bit-exact).
__global__ __launch_bounds__(256) void k_im(const float* __restrict__ ws, float* __restrict__ out) {
    __shared__ __align__(16) unsigned short Zlh[128 * 40];   // [x][k=p*16+ky] hi
    __shared__ __align__(16) unsigned short Zll[128 * 40];   // lo residual
    __shared__ __align__(16) unsigned short Blh[32 * 72];    // [(p,ky)][k=c*32+m] hi
    __shared__ __align__(16) unsigned short Bll[32 * 72];    // lo residual
    __shared__ float2 zm[4][512];
    int t = threadIdx.x, bid = blockIdx.x;                   // b*8 + o-quad
    int b = bid >> 3, o0 = (bid & 7) * 4;
    const unsigned short* tab = (const unsigned short*)(ws + OFF_TAB);

    // ---- channel mix, f32: zm[oo][mode] = sum_i xf[b,i,mode] * w3[o0+oo,i,mode]
    {
        const float* xfr = ws + OFF_XFR + (size_t)(b * 32) * 512 + 2 * t;
        const float* xfi = ws + OFF_XFI + (size_t)(b * 32) * 512 + 2 * t;
        const float* w3  = ws + OFF_WT3 + ((size_t)(o0 * 32) * 512 + 2 * t) * 2;
        float ar[4][2] = {}, ai[4][2] = {};
#pragma unroll 2
        for (int i = 0; i < 32; ++i) {
            const float2 xr2 = *(const float2*)(xfr + (size_t)i * 512);
            const float2 xi2 = *(const float2*)(xfi + (size_t)i * 512);
#pragma unroll
            for (int oo = 0; oo < 4; ++oo) {
                const float4 w4 = *(const float4*)(w3 + (size_t)(oo * 32 + i) * 1024);
                ar[oo][0] = fmaf(xr2.x, w4.x, fmaf(-xi2.x, w4.y, ar[oo][0]));
                ai[oo][0] = fmaf(xr2.x, w4.y, fmaf( xi2.x, w4.x, ai[oo][0]));
                ar[oo][1] = fmaf(xr2.y, w4.z, fmaf(-xi2.y, w4.w, ar[oo][1]));
                ai[oo][1] = fmaf(xr2.y, w4.w, fmaf( xi2.y, w4.z, ai[oo][1]));
            }
        }
#pragma unroll
        for (int oo = 0; oo < 4; ++oo) {
            zm[oo][2 * t]     = make_float2(ar[oo][0], ai[oo][0]);
            zm[oo][2 * t + 1] = make_float2(ar[oo][1], ai[oo][1]);
        }
    }

    int lid = t & 15, q = (t >> 4) & 3, w = t >> 6;

    for (int oo = 0; oo < 4; ++oo) {
        __syncthreads();   // zm ready / previous I1-read of Blh done

        // build Blh/Bll from zm[oo] (complex-as-real with sign trick; hi + residual-lo)
        {
            int n = t >> 3, k0 = (t & 7) * 8;
            int p = n >> 4, ky = n & 15;
            unsigned short hh[8], hl[8];
#pragma unroll
            for (int j = 0; j < 8; ++j) {
                int k = k0 + j, c = k >> 5, m = k & 31;
                float2 v = zm[oo][m * 16 + ky];
                float val = (p == 0) ? (c == 0 ? v.x : v.y) : (c == 0 ? v.y : -v.x);
                unsigned short vh = f2bf(val);
                hh[j] = vh;
                hl[j] = f2bf(val - bf2f(vh));
            }
            ushort4 a, bb;
            a.x = hh[0]; a.y = hh[1]; a.z = hh[2]; a.w = hh[3];
            bb.x = hh[4]; bb.y = hh[5]; bb.z = hh[6]; bb.w = hh[7];
            *(ushort4*)&Blh[n * 72 + k0]     = a;
            *(ushort4*)&Blh[n * 72 + k0 + 4] = bb;
            a.x = hl[0]; a.y = hl[1]; a.z = hl[2]; a.w = hl[3];
            bb.x = hl[4]; bb.y = hl[5]; bb.z = hl[6]; bb.w = hl[7];
            *(ushort4*)&Bll[n * 72 + k0]     = a;
            *(ushort4*)&Bll[n * 72 + k0 + 4] = bb;
        }
        __syncthreads();

        // I1: Z[x][(p,ky)] = sum_k A3[x][k] (Bh+Bl)[(p,ky)][k];  M=128 N=32 K=64
        f32x4 acc[2][2] = {};
#pragma unroll
        for (int ks = 0; ks < 2; ++ks) {
            bf16x8 a0  = *(const bf16x8*)&tab[TAB_A3 + (32 * w + lid) * 64 + ks * 32 + q * 8];
            bf16x8 a1  = *(const bf16x8*)&tab[TAB_A3 + (32 * w + 16 + lid) * 64 + ks * 32 + q * 8];
            bf16x8 bh0 = *(const bf16x8*)&Blh[lid * 72 + ks * 32 + q * 8];
            bf16x8 bh1 = *(const bf16x8*)&Blh[(16 + lid) * 72 + ks * 32 + q * 8];
            bf16x8 bl0 = *(const bf16x8*)&Bll[lid * 72 + ks * 32 + q * 8];
            bf16x8 bl1 = *(const bf16x8*)&Bll[(16 + lid) * 72 + ks * 32 + q * 8];
            acc[0][0] = mfma16(a0, bl0, acc[0][0]);
            acc[0][0] = mfma16(a0, bh0, acc[0][0]);
            acc[0][1] = mfma16(a0, bl1, acc[0][1]);
            acc[0][1] = mfma16(a0, bh1, acc[0][1]);
            acc[1][0] = mfma16(a1, bl0, acc[1][0]);
            acc[1][0] = mfma16(a1, bh0, acc[1][0]);
            acc[1][1] = mfma16(a1, bl1, acc[1][1]);
            acc[1][1] = mfma16(a1, bh1, acc[1][1]);
        }
        // epilogue: Z -> Zlh/Zll[x][p*16+ky] (hi + residual-lo)
#pragma unroll
        for (int mt = 0; mt < 2; ++mt)
#pragma unroll
            for (int nt = 0; nt < 2; ++nt)
#pragma unroll
                for (int r = 0; r < 4; ++r) {
                    float z = acc[mt][nt][r];
                    unsigned short zh = f2bf(z);
                    int idx = (32 * w + mt * 16 + q * 4 + r) * 40 + nt * 16 + lid;
                    Zlh[idx] = zh;
                    Zll[idx] = f2bf(z - bf2f(zh));
                }
        __syncthreads();

        // I2: out[x][y] = sum_k (Zh+Zl)[x][k] E4t[y][k];  M=128 N=128 K=32
        f32x4 acc2[2][8];
#pragma unroll
        for (int mt = 0; mt < 2; ++mt) {
            bf16x8 ah = *(const bf16x8*)&Zlh[(32 * w + mt * 16 + lid) * 40 + q * 8];
            bf16x8 al = *(const bf16x8*)&Zll[(32 * w + mt * 16 + lid) * 40 + q * 8];
#pragma unroll
            for (int nt = 0; nt < 8; ++nt) {
                bf16x8 bb = *(const bf16x8*)&tab[TAB_E4 + (nt * 16 + lid) * 32 + q * 8];
                f32x4 z = {};
                z = mfma16(al, bb, z);
                acc2[mt][nt] = mfma16(ah, bb, z);
            }
        }
        float* og = out + (size_t)(b * 32 + o0 + oo) * 16384;
#pragma unroll
        for (int mt = 0; mt < 2; ++mt)
#pragma unroll
            for (int r = 0; r < 4; ++r)
#pragma unroll
                for (int nt = 0; nt < 8; ++nt)
                    og[(32 * w + mt * 16 + q * 4 + r) * 128 + nt * 16 + lid] = acc2[mt][nt][r];
    }
}

extern "C" void kernel_launch(void* const* d_in, const int* in_sizes, int n_in,
                              void* d_out, int out_size, void* d_ws, size_t ws_size,
                              hipStream_t stream) {
    const float* x  = (const float*)d_in[0];
    const float* wr = (const float*)d_in[1];
    const float* wi = (const float*)d_in[2];
    float* out = (float*)d_out;
    float* ws  = (float*)d_ws;
    k_f <<<dim3(1024), dim3(256), 0, stream>>>(x, wr, wi, ws);
    k_im<<<dim3(256),  dim3(256), 0, stream>>>(ws, out);
}